// Round 1
// baseline (3282.753 us; speedup 1.0000x reference)
//
#include <hip/hip_runtime.h>
#include <stdint.h>

#define N_NODES 100000
#define N_EDGES 3200000
#define IN_FEATS 500
#define HID 64
#define CLS 40
#define KHOPS 10

// ---------------- generic zero ----------------
__global__ void zero_kernel(float4* __restrict__ p, size_t n4) {
  size_t i = (size_t)blockIdx.x * blockDim.x + threadIdx.x;
  size_t stride = (size_t)gridDim.x * blockDim.x;
  float4 z = make_float4(0.f, 0.f, 0.f, 0.f);
  for (; i < n4; i += stride) p[i] = z;
}

// ---------------- CSR build ----------------
__global__ void hist_kernel(const int* __restrict__ dst, int* __restrict__ off) {
  int i = blockIdx.x * blockDim.x + threadIdx.x;
  int stride = gridDim.x * blockDim.x;
  for (int e = i; e < N_EDGES; e += stride) atomicAdd(&off[dst[e] + 1], 1);
}

__launch_bounds__(1024)
__global__ void scan_kernel(int* __restrict__ off, int* __restrict__ cursor) {
  // off[0]=0, off[i]=deg(i-1) for i=1..N. Inclusive scan -> off[i] = start of node i.
  __shared__ int sums[1024];
  const int M = N_NODES + 1;
  int t = threadIdx.x;
  int chunk = (M + 1023) / 1024;  // 98
  int beg = t * chunk;
  int end = beg + chunk; if (end > M) end = M;
  int s = 0;
  for (int i = beg; i < end; ++i) s += off[i];
  sums[t] = s;
  __syncthreads();
  for (int d = 1; d < 1024; d <<= 1) {
    int v = (t >= d) ? sums[t - d] : 0;
    __syncthreads();
    sums[t] += v;
    __syncthreads();
  }
  int run = (t == 0) ? 0 : sums[t - 1];
  for (int i = beg; i < end; ++i) {
    run += off[i];
    off[i] = run;
    if (i < N_NODES) cursor[i] = run;
  }
}

__global__ void fill_kernel(const int* __restrict__ src, const int* __restrict__ dst,
                            const float* __restrict__ w, int* __restrict__ cursor,
                            int2* __restrict__ edges) {
  int i = blockIdx.x * blockDim.x + threadIdx.x;
  int stride = gridDim.x * blockDim.x;
  for (int e = i; e < N_EDGES; e += stride) {
    int p = atomicAdd(&cursor[dst[e]], 1);
    edges[p] = make_int2(src[e], __float_as_int(w[e]));
  }
}

// ---------------- fc1: x = relu(F@W1 + b1) + noise*1e-5 ; nn0 += colsum(x^2) ----------------
__launch_bounds__(256)
__global__ void fc1_kernel(const float* __restrict__ F, const float* __restrict__ W1,
                           const float* __restrict__ bias1, const float* __restrict__ noise,
                           float* __restrict__ x, float* __restrict__ nn0) {
  __shared__ float Fs[64][33];
  __shared__ float Ws[32][64];
  __shared__ float red[64];
  int t = threadIdx.x;
  int tx = t & 15;   // channel group: channels 4*tx..4*tx+3
  int ty = t >> 4;   // node group: nodes 4*ty..4*ty+3
  int nodeBase = blockIdx.x * 64;
  float acc[4][4] = {{0.f}};
  for (int kb = 0; kb < IN_FEATS; kb += 32) {
#pragma unroll
    for (int i = 0; i < 8; ++i) {
      int lin = t + i * 256;
      int r = lin >> 5, c = lin & 31;
      int n = nodeBase + r, k = kb + c;
      Fs[r][c] = (n < N_NODES && k < IN_FEATS) ? F[(size_t)n * IN_FEATS + k] : 0.f;
    }
#pragma unroll
    for (int i = 0; i < 8; ++i) {
      int lin = t + i * 256;
      int r = lin >> 6, c = lin & 63;
      int k = kb + r;
      Ws[r][c] = (k < IN_FEATS) ? W1[(size_t)k * HID + c] : 0.f;
    }
    __syncthreads();
#pragma unroll
    for (int kk = 0; kk < 32; ++kk) {
      float a0 = Fs[4 * ty + 0][kk], a1 = Fs[4 * ty + 1][kk];
      float a2 = Fs[4 * ty + 2][kk], a3 = Fs[4 * ty + 3][kk];
      float w0 = Ws[kk][4 * tx + 0], w1 = Ws[kk][4 * tx + 1];
      float w2 = Ws[kk][4 * tx + 2], w3 = Ws[kk][4 * tx + 3];
      acc[0][0] = fmaf(a0, w0, acc[0][0]); acc[0][1] = fmaf(a0, w1, acc[0][1]);
      acc[0][2] = fmaf(a0, w2, acc[0][2]); acc[0][3] = fmaf(a0, w3, acc[0][3]);
      acc[1][0] = fmaf(a1, w0, acc[1][0]); acc[1][1] = fmaf(a1, w1, acc[1][1]);
      acc[1][2] = fmaf(a1, w2, acc[1][2]); acc[1][3] = fmaf(a1, w3, acc[1][3]);
      acc[2][0] = fmaf(a2, w0, acc[2][0]); acc[2][1] = fmaf(a2, w1, acc[2][1]);
      acc[2][2] = fmaf(a2, w2, acc[2][2]); acc[2][3] = fmaf(a2, w3, acc[2][3]);
      acc[3][0] = fmaf(a3, w0, acc[3][0]); acc[3][1] = fmaf(a3, w1, acc[3][1]);
      acc[3][2] = fmaf(a3, w2, acc[3][2]); acc[3][3] = fmaf(a3, w3, acc[3][3]);
    }
    __syncthreads();
  }
  float np0 = 0.f, np1 = 0.f, np2 = 0.f, np3 = 0.f;
  int ch = 4 * tx;
#pragma unroll
  for (int r = 0; r < 4; ++r) {
    int n = nodeBase + 4 * ty + r;
    if (n < N_NODES) {
      float4 nz = *(const float4*)(noise + (size_t)n * HID + ch);
      float v0 = fmaxf(acc[r][0] + bias1[ch + 0], 0.f) + nz.x * 1e-5f;
      float v1 = fmaxf(acc[r][1] + bias1[ch + 1], 0.f) + nz.y * 1e-5f;
      float v2 = fmaxf(acc[r][2] + bias1[ch + 2], 0.f) + nz.z * 1e-5f;
      float v3 = fmaxf(acc[r][3] + bias1[ch + 3], 0.f) + nz.w * 1e-5f;
      float4 vv = make_float4(v0, v1, v2, v3);
      *(float4*)(x + (size_t)n * HID + ch) = vv;
      np0 = fmaf(v0, v0, np0); np1 = fmaf(v1, v1, np1);
      np2 = fmaf(v2, v2, np2); np3 = fmaf(v3, v3, np3);
    }
  }
  if (t < 64) red[t] = 0.f;
  __syncthreads();
  atomicAdd(&red[ch + 0], np0); atomicAdd(&red[ch + 1], np1);
  atomicAdd(&red[ch + 2], np2); atomicAdd(&red[ch + 3], np3);
  __syncthreads();
  if (t < 64) atomicAdd(&nn0[t], red[t]);
}

// ---------------- SpMM (CSR gather) + fused d1,d2 dots ----------------
__launch_bounds__(256)
__global__ void spmm_kernel(const int2* __restrict__ edges, const int* __restrict__ off,
                            const float* __restrict__ last, const float* __restrict__ second,
                            float* __restrict__ h, float* __restrict__ dslot) {
  __shared__ float red[128];
  int t = threadIdx.x;
  int lane = t & 63;
  int wid = t >> 6;
  if (t < 128) red[t] = 0.f;
  __syncthreads();
  float d1 = 0.f, d2 = 0.f;
  int wg = blockIdx.x * 4 + wid;
  int nw = gridDim.x * 4;
  for (int n = wg; n < N_NODES; n += nw) {
    int beg = off[n], end = off[n + 1];
    float acc = 0.f;
    for (int base = beg; base < end; base += 64) {
      int cnt = end - base; if (cnt > 64) cnt = 64;
      int li = lane; if (li >= cnt) li = cnt - 1;
      int2 e = edges[base + li];
      int j = 0;
      for (; j + 4 <= cnt; j += 4) {
        int s0 = __shfl(e.x, j + 0); float w0 = __int_as_float(__shfl(e.y, j + 0));
        int s1 = __shfl(e.x, j + 1); float w1 = __int_as_float(__shfl(e.y, j + 1));
        int s2 = __shfl(e.x, j + 2); float w2 = __int_as_float(__shfl(e.y, j + 2));
        int s3 = __shfl(e.x, j + 3); float w3 = __int_as_float(__shfl(e.y, j + 3));
        float v0 = last[(size_t)s0 * HID + lane];
        float v1 = last[(size_t)s1 * HID + lane];
        float v2 = last[(size_t)s2 * HID + lane];
        float v3 = last[(size_t)s3 * HID + lane];
        acc = fmaf(w0, v0, acc); acc = fmaf(w1, v1, acc);
        acc = fmaf(w2, v2, acc); acc = fmaf(w3, v3, acc);
      }
      for (; j < cnt; ++j) {
        int s0 = __shfl(e.x, j); float w0 = __int_as_float(__shfl(e.y, j));
        acc = fmaf(w0, last[(size_t)s0 * HID + lane], acc);
      }
    }
    size_t o = (size_t)n * HID + lane;
    float l = last[o], s = second[o];
    h[o] = acc;
    d1 = fmaf(acc, l, d1);
    d2 = fmaf(acc, s, d2);
  }
  atomicAdd(&red[lane], d1);
  atomicAdd(&red[64 + lane], d2);
  __syncthreads();
  if (t < 128) atomicAdd(&dslot[t], red[t]);  // dslot[0..63]=d1, [64..127]=d2
}

// ---------------- pass B: h -= d1*last + d2*second ; nn += colsum(h^2) ----------------
__launch_bounds__(256)
__global__ void passB_kernel(float4* __restrict__ h4, const float4* __restrict__ l4,
                             const float4* __restrict__ s4, const float* __restrict__ dslot,
                             float* __restrict__ nnslot) {
  __shared__ float red[64];
  int t = threadIdx.x;
  int q = t & 15;
  float4 D1 = ((const float4*)dslot)[q];
  float4 D2 = ((const float4*)(dslot + 64))[q];
  float nx = 0.f, ny = 0.f, nz = 0.f, nw = 0.f;
  int row0 = blockIdx.x * 16 + (t >> 4);
  int rstride = gridDim.x * 16;
  for (int n = row0; n < N_NODES; n += rstride) {
    size_t idx = (size_t)n * 16 + q;
    float4 h = h4[idx];
    float4 l = l4[idx];
    float4 s = s4[idx];
    h.x -= D1.x * l.x + D2.x * s.x;
    h.y -= D1.y * l.y + D2.y * s.y;
    h.z -= D1.z * l.z + D2.z * s.z;
    h.w -= D1.w * l.w + D2.w * s.w;
    h4[idx] = h;
    nx = fmaf(h.x, h.x, nx); ny = fmaf(h.y, h.y, ny);
    nz = fmaf(h.z, h.z, nz); nw = fmaf(h.w, h.w, nw);
  }
  if (t < 64) red[t] = 0.f;
  __syncthreads();
  int c0 = q * 4;
  atomicAdd(&red[c0 + 0], nx); atomicAdd(&red[c0 + 1], ny);
  atomicAdd(&red[c0 + 2], nz); atomicAdd(&red[c0 + 3], nw);
  __syncthreads();
  if (t < 64) atomicAdd(&nnslot[t], red[t]);
}

// ---------------- pass C: h /= max(sqrt(nn),eps) ; rst (+)= alpha[:,icol]*h ----------------
__launch_bounds__(256)
__global__ void passC_kernel(float4* __restrict__ h4, float4* __restrict__ rst4,
                             const float* __restrict__ nnslot, const float* __restrict__ alpha,
                             int icol, int accum) {
  int t = threadIdx.x;
  int q = t & 15;
  int c0 = q * 4;
  float4 nn = ((const float4*)nnslot)[q];
  float4 inv;
  inv.x = 1.f / fmaxf(sqrtf(nn.x), 1e-8f);
  inv.y = 1.f / fmaxf(sqrtf(nn.y), 1e-8f);
  inv.z = 1.f / fmaxf(sqrtf(nn.z), 1e-8f);
  inv.w = 1.f / fmaxf(sqrtf(nn.w), 1e-8f);
  float4 al;
  al.x = alpha[(size_t)(c0 + 0) * (KHOPS + 1) + icol];
  al.y = alpha[(size_t)(c0 + 1) * (KHOPS + 1) + icol];
  al.z = alpha[(size_t)(c0 + 2) * (KHOPS + 1) + icol];
  al.w = alpha[(size_t)(c0 + 3) * (KHOPS + 1) + icol];
  int row0 = blockIdx.x * 16 + (t >> 4);
  int rstride = gridDim.x * 16;
  for (int n = row0; n < N_NODES; n += rstride) {
    size_t idx = (size_t)n * 16 + q;
    float4 h = h4[idx];
    h.x *= inv.x; h.y *= inv.y; h.z *= inv.z; h.w *= inv.w;
    h4[idx] = h;
    float4 r;
    if (accum) {
      r = rst4[idx];
      r.x = fmaf(al.x, h.x, r.x); r.y = fmaf(al.y, h.y, r.y);
      r.z = fmaf(al.z, h.z, r.z); r.w = fmaf(al.w, h.w, r.w);
    } else {
      r.x = al.x * h.x; r.y = al.y * h.y; r.z = al.z * h.z; r.w = al.w * h.w;
    }
    rst4[idx] = r;
  }
}

// ---------------- fc2: out = rst @ W2 + b2 ----------------
__launch_bounds__(256)
__global__ void gemm2_kernel(const float* __restrict__ rst, const float* __restrict__ W2,
                             const float* __restrict__ bias2, float* __restrict__ out) {
  __shared__ float W2s[64 * 40];
  __shared__ float R[64][65];
  int t = threadIdx.x;
  for (int i = t; i < 64 * 40; i += 256) W2s[i] = W2[i];
  int nodeBase = blockIdx.x * 64;
  for (int i = t; i < 64 * 16; i += 256) {
    int r = i >> 4, c4 = (i & 15) * 4;
    int n = nodeBase + r;
    float4 v = make_float4(0.f, 0.f, 0.f, 0.f);
    if (n < N_NODES) v = *(const float4*)(rst + (size_t)n * HID + c4);
    R[r][c4 + 0] = v.x; R[r][c4 + 1] = v.y; R[r][c4 + 2] = v.z; R[r][c4 + 3] = v.w;
  }
  __syncthreads();
  int node = t >> 2;
  int cls0 = (t & 3) * 10;
  float o[10];
#pragma unroll
  for (int j = 0; j < 10; ++j) o[j] = bias2[cls0 + j];
#pragma unroll 4
  for (int k = 0; k < 64; ++k) {
    float rv = R[node][k];
    const float* wrow = &W2s[k * 40 + cls0];
#pragma unroll
    for (int j = 0; j < 10; ++j) o[j] = fmaf(rv, wrow[j], o[j]);
  }
  int n = nodeBase + node;
  if (n < N_NODES) {
#pragma unroll
    for (int j = 0; j < 10; ++j) out[(size_t)n * CLS + cls0 + j] = o[j];
  }
}

extern "C" void kernel_launch(void* const* d_in, const int* in_sizes, int n_in,
                              void* d_out, int out_size, void* d_ws, size_t ws_size,
                              hipStream_t stream) {
  (void)in_sizes; (void)n_in; (void)out_size;
  const float* features  = (const float*)d_in[0];
  const float* noise     = (const float*)d_in[1];
  const float* norm_A    = (const float*)d_in[2];
  const float* W1        = (const float*)d_in[3];
  const float* b1        = (const float*)d_in[4];
  const float* W2        = (const float*)d_in[5];
  const float* b2        = (const float*)d_in[6];
  const float* alpha     = (const float*)d_in[7];
  const int*   edge_index= (const int*)d_in[8];
  float* out = (float*)d_out;

  char* ws = (char*)d_ws;
  const size_t NB = (size_t)N_NODES * HID * sizeof(float);  // 25,600,000 B
  const size_t CURSOR_PAD = 400128;                          // N*4 padded to 16B
  float* hA    = (float*)(ws);
  float* hC    = (float*)(ws + NB);
  float* rst   = (float*)(ws + 2 * NB);
  int2*  edges = (int2*)(ws + 3 * NB);                       // E*8 = 25,600,000 B
  int*   cursor= (int*)(ws + 4 * NB);
  char*  zbase = ws + 4 * NB + CURSOR_PAD;
  float* hB    = (float*)(zbase);                            // NB, must start zeroed
  int*   off   = (int*)(zbase + NB);                         // (N+1)*4, padded to 400128
  float* dots  = (float*)(zbase + NB + 400128);              // (K+1)*192 floats
  const size_t zspan = NB + 400128 + (size_t)(KHOPS + 1) * 192 * 4;  // 26,008,576 B
  const size_t total = 4 * NB + CURSOR_PAD + zspan;          // ~128.81 MB
  if (ws_size < total) return;  // fail loudly (wrong output) rather than corrupt memory

  // 1) zero second_last (hB) + off + dots in one contiguous span
  zero_kernel<<<4096, 256, 0, stream>>>((float4*)zbase, zspan / 16);
  // 2) CSR build (per-call: inputs are restored before every timed launch)
  hist_kernel<<<2048, 256, 0, stream>>>(edge_index + N_EDGES, off);
  scan_kernel<<<1, 1024, 0, stream>>>(off, cursor);
  fill_kernel<<<2048, 256, 0, stream>>>(edge_index, edge_index + N_EDGES, norm_A, cursor, edges);
  // 3) fc1 -> hA (raw x), colsum(x^2) -> dots slot0 nn (at +128)
  fc1_kernel<<<(N_NODES + 63) / 64, 256, 0, stream>>>(features, W1, b1, noise, hA, dots + 128);
  // 4) normalize h0 in place, rst = alpha[:,0]*h0
  passC_kernel<<<1024, 256, 0, stream>>>((float4*)hA, (float4*)rst, dots + 128, alpha, 0, 0);
  // 5) K hops: (second,last,cur) rotate through (hB,hA,hC)
  float* second = hB; float* last = hA; float* cur = hC;
  for (int i = 1; i <= KHOPS; ++i) {
    float* dslot = dots + (size_t)i * 192;  // d1[64], d2[64], nn[64]
    spmm_kernel<<<2048, 256, 0, stream>>>(edges, off, last, second, cur, dslot);
    passB_kernel<<<1024, 256, 0, stream>>>((float4*)cur, (const float4*)last,
                                           (const float4*)second, dslot, dslot + 128);
    passC_kernel<<<1024, 256, 0, stream>>>((float4*)cur, (float4*)rst, dslot + 128, alpha, i, 1);
    float* tmp = second; second = last; last = cur; cur = tmp;
  }
  // 6) out = rst @ W2 + b2
  gemm2_kernel<<<(N_NODES + 63) / 64, 256, 0, stream>>>(rst, W2, b2, out);
}

// Round 2
// 2921.723 us; speedup vs baseline: 1.1236x; 1.1236x over previous
//
#include <hip/hip_runtime.h>
#include <stdint.h>

#define N_NODES 100000
#define N_EDGES 3200000
#define IN_FEATS 500
#define HID 64
#define CLS 40
#define KHOPS 10
#define KT 32

// ---------------- generic zero ----------------
__global__ void zero_kernel(float4* __restrict__ p, size_t n4) {
  size_t i = (size_t)blockIdx.x * blockDim.x + threadIdx.x;
  size_t stride = (size_t)gridDim.x * blockDim.x;
  float4 z = make_float4(0.f, 0.f, 0.f, 0.f);
  for (; i < n4; i += stride) p[i] = z;
}

// ---------------- CSR build ----------------
__global__ void hist_kernel(const int* __restrict__ dst, int* __restrict__ off) {
  int i = blockIdx.x * blockDim.x + threadIdx.x;
  int stride = gridDim.x * blockDim.x;
  for (int e = i; e < N_EDGES; e += stride) atomicAdd(&off[dst[e] + 1], 1);
}

__launch_bounds__(1024)
__global__ void scan_kernel(int* __restrict__ off, int* __restrict__ cursor) {
  __shared__ int sums[1024];
  const int M = N_NODES + 1;
  int t = threadIdx.x;
  int chunk = (M + 1023) / 1024;
  int beg = t * chunk;
  int end = beg + chunk; if (end > M) end = M;
  int s = 0;
  for (int i = beg; i < end; ++i) s += off[i];
  sums[t] = s;
  __syncthreads();
  for (int d = 1; d < 1024; d <<= 1) {
    int v = (t >= d) ? sums[t - d] : 0;
    __syncthreads();
    sums[t] += v;
    __syncthreads();
  }
  int run = (t == 0) ? 0 : sums[t - 1];
  for (int i = beg; i < end; ++i) {
    run += off[i];
    off[i] = run;
    if (i < N_NODES) cursor[i] = run;
  }
}

__global__ void fill_kernel(const int* __restrict__ src, const int* __restrict__ dst,
                            const float* __restrict__ w, int* __restrict__ cursor,
                            int2* __restrict__ edges) {
  int i = blockIdx.x * blockDim.x + threadIdx.x;
  int stride = gridDim.x * blockDim.x;
  for (int e = i; e < N_EDGES; e += stride) {
    int p = atomicAdd(&cursor[dst[e]], 1);
    edges[p] = make_int2(src[e], __float_as_int(w[e]));
  }
}

// ---------------- fc1: x_raw = relu(F@W1 + b1) + noise*1e-5 ; nn0 += colsum(x^2) ----------------
// 128-node x 64-ch tile, 256 threads, thread = 8 nodes x 4 ch, K-tile 32,
// register double-buffered global->LDS staging, transposed F tile for b128 reads.
__launch_bounds__(256)
__global__ void fc1_kernel(const float* __restrict__ F, const float* __restrict__ W1,
                           const float* __restrict__ bias1, const float* __restrict__ noise,
                           float* __restrict__ x, float* __restrict__ nn0) {
  __shared__ float Fs[KT][132];   // [k][node], pad 132 keeps b128 reads aligned + conflict-free
  __shared__ float Ws[KT][64];
  __shared__ float red[64];
  const int t = threadIdx.x;
  const int tx = t & 15;          // channel group
  const int ty = t >> 4;          // node group
  const int c0 = tx * 4;
  const int n0 = ty * 8;
  const int nodeBase = blockIdx.x * 128;
  // staging indices
  const int fk = (t & 7) * 4;     // k offset in tile
  const int fn = t >> 3;          // node 0..31 within 32-group
  const int wr = t >> 3;          // W row 0..31
  const int wc = (t & 7) * 8;     // W col base

  float4 fr[4];
  float4 w0r, w1r;

  // tile 0 prefetch
  {
    const int kb = 0;
#pragma unroll
    for (int p = 0; p < 4; ++p) {
      int n = nodeBase + fn + 32 * p;
      int k = kb + fk;
      float4 v = make_float4(0.f, 0.f, 0.f, 0.f);
      if (n < N_NODES && k + 3 < IN_FEATS) v = *(const float4*)(F + (size_t)n * IN_FEATS + k);
      fr[p] = v;
    }
    int k = kb + wr;
    float4 a = make_float4(0.f, 0.f, 0.f, 0.f), b = a;
    if (k < IN_FEATS) {
      a = *(const float4*)(W1 + (size_t)k * HID + wc);
      b = *(const float4*)(W1 + (size_t)k * HID + wc + 4);
    }
    w0r = a; w1r = b;
  }

  float acc[8][4];
#pragma unroll
  for (int i = 0; i < 8; ++i)
#pragma unroll
    for (int j = 0; j < 4; ++j) acc[i][j] = 0.f;

  const int NTILE = (IN_FEATS + KT - 1) / KT;  // 16
  for (int tile = 0; tile < NTILE; ++tile) {
    __syncthreads();
    // store prefetched regs -> LDS (transposed F)
#pragma unroll
    for (int p = 0; p < 4; ++p) {
      Fs[fk + 0][fn + 32 * p] = fr[p].x;
      Fs[fk + 1][fn + 32 * p] = fr[p].y;
      Fs[fk + 2][fn + 32 * p] = fr[p].z;
      Fs[fk + 3][fn + 32 * p] = fr[p].w;
    }
    *(float4*)&Ws[wr][wc] = w0r;
    *(float4*)&Ws[wr][wc + 4] = w1r;
    __syncthreads();
    // prefetch next tile (in flight during compute)
    if (tile + 1 < NTILE) {
      const int kb = (tile + 1) * KT;
#pragma unroll
      for (int p = 0; p < 4; ++p) {
        int n = nodeBase + fn + 32 * p;
        int k = kb + fk;
        float4 v = make_float4(0.f, 0.f, 0.f, 0.f);
        if (n < N_NODES && k + 3 < IN_FEATS) v = *(const float4*)(F + (size_t)n * IN_FEATS + k);
        fr[p] = v;
      }
      int k = kb + wr;
      float4 a = make_float4(0.f, 0.f, 0.f, 0.f), b = a;
      if (k < IN_FEATS) {
        a = *(const float4*)(W1 + (size_t)k * HID + wc);
        b = *(const float4*)(W1 + (size_t)k * HID + wc + 4);
      }
      w0r = a; w1r = b;
    }
    // compute
#pragma unroll 8
    for (int kk = 0; kk < KT; ++kk) {
      float4 fa = *(float4*)&Fs[kk][n0];
      float4 fb = *(float4*)&Fs[kk][n0 + 4];
      float4 wv = *(float4*)&Ws[kk][c0];
      acc[0][0] = fmaf(fa.x, wv.x, acc[0][0]); acc[0][1] = fmaf(fa.x, wv.y, acc[0][1]);
      acc[0][2] = fmaf(fa.x, wv.z, acc[0][2]); acc[0][3] = fmaf(fa.x, wv.w, acc[0][3]);
      acc[1][0] = fmaf(fa.y, wv.x, acc[1][0]); acc[1][1] = fmaf(fa.y, wv.y, acc[1][1]);
      acc[1][2] = fmaf(fa.y, wv.z, acc[1][2]); acc[1][3] = fmaf(fa.y, wv.w, acc[1][3]);
      acc[2][0] = fmaf(fa.z, wv.x, acc[2][0]); acc[2][1] = fmaf(fa.z, wv.y, acc[2][1]);
      acc[2][2] = fmaf(fa.z, wv.z, acc[2][2]); acc[2][3] = fmaf(fa.z, wv.w, acc[2][3]);
      acc[3][0] = fmaf(fa.w, wv.x, acc[3][0]); acc[3][1] = fmaf(fa.w, wv.y, acc[3][1]);
      acc[3][2] = fmaf(fa.w, wv.z, acc[3][2]); acc[3][3] = fmaf(fa.w, wv.w, acc[3][3]);
      acc[4][0] = fmaf(fb.x, wv.x, acc[4][0]); acc[4][1] = fmaf(fb.x, wv.y, acc[4][1]);
      acc[4][2] = fmaf(fb.x, wv.z, acc[4][2]); acc[4][3] = fmaf(fb.x, wv.w, acc[4][3]);
      acc[5][0] = fmaf(fb.y, wv.x, acc[5][0]); acc[5][1] = fmaf(fb.y, wv.y, acc[5][1]);
      acc[5][2] = fmaf(fb.y, wv.z, acc[5][2]); acc[5][3] = fmaf(fb.y, wv.w, acc[5][3]);
      acc[6][0] = fmaf(fb.z, wv.x, acc[6][0]); acc[6][1] = fmaf(fb.z, wv.y, acc[6][1]);
      acc[6][2] = fmaf(fb.z, wv.z, acc[6][2]); acc[6][3] = fmaf(fb.z, wv.w, acc[6][3]);
      acc[7][0] = fmaf(fb.w, wv.x, acc[7][0]); acc[7][1] = fmaf(fb.w, wv.y, acc[7][1]);
      acc[7][2] = fmaf(fb.w, wv.z, acc[7][2]); acc[7][3] = fmaf(fb.w, wv.w, acc[7][3]);
    }
  }

  // epilogue
  float4 bb = *(const float4*)(bias1 + c0);
  float np0 = 0.f, np1 = 0.f, np2 = 0.f, np3 = 0.f;
#pragma unroll
  for (int i = 0; i < 8; ++i) {
    int n = nodeBase + n0 + i;
    if (n < N_NODES) {
      float4 nz = *(const float4*)(noise + (size_t)n * HID + c0);
      float v0 = fmaxf(acc[i][0] + bb.x, 0.f) + nz.x * 1e-5f;
      float v1 = fmaxf(acc[i][1] + bb.y, 0.f) + nz.y * 1e-5f;
      float v2 = fmaxf(acc[i][2] + bb.z, 0.f) + nz.z * 1e-5f;
      float v3 = fmaxf(acc[i][3] + bb.w, 0.f) + nz.w * 1e-5f;
      *(float4*)(x + (size_t)n * HID + c0) = make_float4(v0, v1, v2, v3);
      np0 = fmaf(v0, v0, np0); np1 = fmaf(v1, v1, np1);
      np2 = fmaf(v2, v2, np2); np3 = fmaf(v3, v3, np3);
    }
  }
  if (t < 64) red[t] = 0.f;
  __syncthreads();
  atomicAdd(&red[c0 + 0], np0); atomicAdd(&red[c0 + 1], np1);
  atomicAdd(&red[c0 + 2], np2); atomicAdd(&red[c0 + 3], np3);
  __syncthreads();
  if (t < 64) atomicAdd(&nn0[t], red[t]);
}

// ---------------- SpMM on RAW last, scale folded: h = sig_l * (A @ last_raw) ----------------
// also accumulates d1raw = h . last_raw, d2raw = h . second_raw
__launch_bounds__(256)
__global__ void spmm_kernel(const int2* __restrict__ edges, const int* __restrict__ off,
                            const float* __restrict__ lastr, const float* __restrict__ secondr,
                            const float* __restrict__ nn_l,
                            float* __restrict__ h, float* __restrict__ dslot) {
  __shared__ float red[128];
  int t = threadIdx.x;
  int lane = t & 63;
  int wid = t >> 6;
  if (t < 128) red[t] = 0.f;
  __syncthreads();
  float sig = 1.f / fmaxf(sqrtf(nn_l[lane]), 1e-8f);
  float d1 = 0.f, d2 = 0.f;
  int wg = blockIdx.x * 4 + wid;
  int nw = gridDim.x * 4;
  for (int n = wg; n < N_NODES; n += nw) {
    int beg = off[n], end = off[n + 1];
    float acc = 0.f;
    for (int base = beg; base < end; base += 64) {
      int cnt = end - base; if (cnt > 64) cnt = 64;
      int li = (lane < cnt) ? lane : (cnt - 1);
      int2 e = edges[base + li];
      int j = 0;
      for (; j + 8 <= cnt; j += 8) {
        int s0 = __shfl(e.x, j + 0); float w0 = __int_as_float(__shfl(e.y, j + 0));
        int s1 = __shfl(e.x, j + 1); float w1 = __int_as_float(__shfl(e.y, j + 1));
        int s2 = __shfl(e.x, j + 2); float w2 = __int_as_float(__shfl(e.y, j + 2));
        int s3 = __shfl(e.x, j + 3); float w3 = __int_as_float(__shfl(e.y, j + 3));
        int s4 = __shfl(e.x, j + 4); float w4 = __int_as_float(__shfl(e.y, j + 4));
        int s5 = __shfl(e.x, j + 5); float w5 = __int_as_float(__shfl(e.y, j + 5));
        int s6 = __shfl(e.x, j + 6); float w6 = __int_as_float(__shfl(e.y, j + 6));
        int s7 = __shfl(e.x, j + 7); float w7 = __int_as_float(__shfl(e.y, j + 7));
        float v0 = lastr[(size_t)s0 * HID + lane];
        float v1 = lastr[(size_t)s1 * HID + lane];
        float v2 = lastr[(size_t)s2 * HID + lane];
        float v3 = lastr[(size_t)s3 * HID + lane];
        float v4 = lastr[(size_t)s4 * HID + lane];
        float v5 = lastr[(size_t)s5 * HID + lane];
        float v6 = lastr[(size_t)s6 * HID + lane];
        float v7 = lastr[(size_t)s7 * HID + lane];
        acc = fmaf(w0, v0, acc); acc = fmaf(w1, v1, acc);
        acc = fmaf(w2, v2, acc); acc = fmaf(w3, v3, acc);
        acc = fmaf(w4, v4, acc); acc = fmaf(w5, v5, acc);
        acc = fmaf(w6, v6, acc); acc = fmaf(w7, v7, acc);
      }
      for (; j < cnt; ++j) {
        int s0 = __shfl(e.x, j); float w0 = __int_as_float(__shfl(e.y, j));
        acc = fmaf(w0, lastr[(size_t)s0 * HID + lane], acc);
      }
    }
    acc *= sig;  // h = A @ (sig * last_raw)  (exact: per-channel scale, A linear)
    size_t o = (size_t)n * HID + lane;
    float l = lastr[o], s = secondr[o];
    h[o] = acc;
    d1 = fmaf(acc, l, d1);
    d2 = fmaf(acc, s, d2);
  }
  atomicAdd(&red[lane], d1);
  atomicAdd(&red[64 + lane], d2);
  __syncthreads();
  if (t < 128) atomicAdd(&dslot[t], red[t]);  // [0:64]=d1raw, [64:128]=d2raw
}

// ---------------- passB: h -= sigl^2*d1raw*l_raw + sigs^2*d2raw*s_raw ;
//                  nn += colsum(h^2) ; rst (+)= (alpha[:,prevcol]*sigl) * l_raw ----------------
__launch_bounds__(256)
__global__ void passB_kernel(float4* __restrict__ h4, const float4* __restrict__ l4,
                             const float4* __restrict__ s4, float* __restrict__ dcur,
                             const float* __restrict__ nn_l, const float* __restrict__ nn_s,
                             const float* __restrict__ alpha, int prevcol, int accum,
                             float4* __restrict__ rst4) {
  __shared__ float red[64];
  int t = threadIdx.x;
  int q = t & 15;
  int c0 = q * 4;
  float4 NL = ((const float4*)nn_l)[q];
  float4 NS = ((const float4*)nn_s)[q];
  float4 D1 = ((const float4*)dcur)[q];
  float4 D2 = ((const float4*)(dcur + 64))[q];
  float4 sigl, sigs;
  sigl.x = 1.f / fmaxf(sqrtf(NL.x), 1e-8f); sigl.y = 1.f / fmaxf(sqrtf(NL.y), 1e-8f);
  sigl.z = 1.f / fmaxf(sqrtf(NL.z), 1e-8f); sigl.w = 1.f / fmaxf(sqrtf(NL.w), 1e-8f);
  sigs.x = 1.f / fmaxf(sqrtf(NS.x), 1e-8f); sigs.y = 1.f / fmaxf(sqrtf(NS.y), 1e-8f);
  sigs.z = 1.f / fmaxf(sqrtf(NS.z), 1e-8f); sigs.w = 1.f / fmaxf(sqrtf(NS.w), 1e-8f);
  float4 C1, C2, AL;
  C1.x = sigl.x * sigl.x * D1.x; C1.y = sigl.y * sigl.y * D1.y;
  C1.z = sigl.z * sigl.z * D1.z; C1.w = sigl.w * sigl.w * D1.w;
  C2.x = sigs.x * sigs.x * D2.x; C2.y = sigs.y * sigs.y * D2.y;
  C2.z = sigs.z * sigs.z * D2.z; C2.w = sigs.w * sigs.w * D2.w;
  AL.x = alpha[(size_t)(c0 + 0) * (KHOPS + 1) + prevcol] * sigl.x;
  AL.y = alpha[(size_t)(c0 + 1) * (KHOPS + 1) + prevcol] * sigl.y;
  AL.z = alpha[(size_t)(c0 + 2) * (KHOPS + 1) + prevcol] * sigl.z;
  AL.w = alpha[(size_t)(c0 + 3) * (KHOPS + 1) + prevcol] * sigl.w;
  float nx = 0.f, ny = 0.f, nz = 0.f, nw = 0.f;
  int row0 = blockIdx.x * 16 + (t >> 4);
  int rstride = gridDim.x * 16;
  for (int n = row0; n < N_NODES; n += rstride) {
    size_t idx = (size_t)n * 16 + q;
    float4 h = h4[idx];
    float4 l = l4[idx];
    float4 s = s4[idx];
    h.x -= C1.x * l.x + C2.x * s.x;
    h.y -= C1.y * l.y + C2.y * s.y;
    h.z -= C1.z * l.z + C2.z * s.z;
    h.w -= C1.w * l.w + C2.w * s.w;
    h4[idx] = h;
    nx = fmaf(h.x, h.x, nx); ny = fmaf(h.y, h.y, ny);
    nz = fmaf(h.z, h.z, nz); nw = fmaf(h.w, h.w, nw);
    float4 r;
    if (accum) {
      r = rst4[idx];
      r.x = fmaf(AL.x, l.x, r.x); r.y = fmaf(AL.y, l.y, r.y);
      r.z = fmaf(AL.z, l.z, r.z); r.w = fmaf(AL.w, l.w, r.w);
    } else {
      r.x = AL.x * l.x; r.y = AL.y * l.y; r.z = AL.z * l.z; r.w = AL.w * l.w;
    }
    rst4[idx] = r;
  }
  if (t < 64) red[t] = 0.f;
  __syncthreads();
  atomicAdd(&red[c0 + 0], nx); atomicAdd(&red[c0 + 1], ny);
  atomicAdd(&red[c0 + 2], nz); atomicAdd(&red[c0 + 3], nw);
  __syncthreads();
  if (t < 64) atomicAdd(&dcur[128 + t], red[t]);
}

// ---------------- fc2: out = (rst + coef*hK_raw) @ W2 + b2, coef = alpha[:,K]*sigK ----------------
__launch_bounds__(256)
__global__ void gemm2_kernel(const float* __restrict__ rst, const float* __restrict__ hK,
                             const float* __restrict__ nnK, const float* __restrict__ alpha,
                             const float* __restrict__ W2, const float* __restrict__ bias2,
                             float* __restrict__ out) {
  __shared__ float W2s[HID * CLS];
  __shared__ float R[64][65];
  __shared__ float coef[64];
  int t = threadIdx.x;
  if (t < 64) coef[t] = alpha[(size_t)t * (KHOPS + 1) + KHOPS] / fmaxf(sqrtf(nnK[t]), 1e-8f);
  for (int i = t; i < HID * CLS; i += 256) W2s[i] = W2[i];
  int nodeBase = blockIdx.x * 64;
  __syncthreads();
  for (int i = t; i < 64 * 16; i += 256) {
    int r = i >> 4, c4 = (i & 15) * 4;
    int n = nodeBase + r;
    if (n < N_NODES) {
      float4 rv = *(const float4*)(rst + (size_t)n * HID + c4);
      float4 hv = *(const float4*)(hK + (size_t)n * HID + c4);
      R[r][c4 + 0] = rv.x + coef[c4 + 0] * hv.x;
      R[r][c4 + 1] = rv.y + coef[c4 + 1] * hv.y;
      R[r][c4 + 2] = rv.z + coef[c4 + 2] * hv.z;
      R[r][c4 + 3] = rv.w + coef[c4 + 3] * hv.w;
    } else {
      R[r][c4 + 0] = 0.f; R[r][c4 + 1] = 0.f; R[r][c4 + 2] = 0.f; R[r][c4 + 3] = 0.f;
    }
  }
  __syncthreads();
  int node = t >> 2;
  int cls0 = (t & 3) * 10;
  float o[10];
#pragma unroll
  for (int j = 0; j < 10; ++j) o[j] = bias2[cls0 + j];
#pragma unroll 4
  for (int k = 0; k < HID; ++k) {
    float rv = R[node][k];
    const float* wrow = &W2s[k * CLS + cls0];
#pragma unroll
    for (int j = 0; j < 10; ++j) o[j] = fmaf(rv, wrow[j], o[j]);
  }
  int n = nodeBase + node;
  if (n < N_NODES) {
#pragma unroll
    for (int j = 0; j < 10; ++j) out[(size_t)n * CLS + cls0 + j] = o[j];
  }
}

extern "C" void kernel_launch(void* const* d_in, const int* in_sizes, int n_in,
                              void* d_out, int out_size, void* d_ws, size_t ws_size,
                              hipStream_t stream) {
  (void)in_sizes; (void)n_in; (void)out_size;
  const float* features  = (const float*)d_in[0];
  const float* noise     = (const float*)d_in[1];
  const float* norm_A    = (const float*)d_in[2];
  const float* W1        = (const float*)d_in[3];
  const float* b1        = (const float*)d_in[4];
  const float* W2        = (const float*)d_in[5];
  const float* b2        = (const float*)d_in[6];
  const float* alpha     = (const float*)d_in[7];
  const int*   edge_index= (const int*)d_in[8];
  float* out = (float*)d_out;

  char* ws = (char*)d_ws;
  const size_t NB = (size_t)N_NODES * HID * sizeof(float);  // 25,600,000 B
  const size_t CURSOR_PAD = 400128;
  float* hA    = (float*)(ws);
  float* hC    = (float*)(ws + NB);
  float* rst   = (float*)(ws + 2 * NB);
  int2*  edges = (int2*)(ws + 3 * NB);
  int*   cursor= (int*)(ws + 4 * NB);
  char*  zbase = ws + 4 * NB + CURSOR_PAD;
  float* hB    = (float*)(zbase);                            // NB, zeroed (second_0)
  int*   off   = (int*)(zbase + NB);                         // padded to 400128
  float* dots  = (float*)(zbase + NB + 400128);              // 12 slots of 192 floats
  const size_t zspan = NB + 400128 + (size_t)12 * 192 * 4;
  const size_t total = 4 * NB + CURSOR_PAD + zspan;
  if (ws_size < total) return;

  // dslot(i) for i in [-1..K]; layout per slot: d1raw[0:64], d2raw[64:128], nn[128:192]
  // slot -1 stays zero (sigma for the zero 'second' at hop 1; d2raw=0 makes C2 exactly 0)
  zero_kernel<<<4096, 256, 0, stream>>>((float4*)zbase, zspan / 16);
  hist_kernel<<<2048, 256, 0, stream>>>(edge_index + N_EDGES, off);
  scan_kernel<<<1, 1024, 0, stream>>>(off, cursor);
  fill_kernel<<<2048, 256, 0, stream>>>(edge_index, edge_index + N_EDGES, norm_A, cursor, edges);
  // fc1 -> hA = x_raw (unnormalized h0), nn0 -> slot0 nn
  fc1_kernel<<<(N_NODES + 127) / 128, 256, 0, stream>>>(features, W1, b1, noise, hA,
                                                        dots + 1 * 192 + 128);
  float* second = hB; float* last = hA; float* cur = hC;
  for (int i = 1; i <= KHOPS; ++i) {
    float* dc = dots + (size_t)(i + 1) * 192;
    float* nl = dots + (size_t)(i)     * 192 + 128;  // nn of last (slot i-1)
    float* ns = dots + (size_t)(i - 1) * 192 + 128;  // nn of second (slot i-2)
    spmm_kernel<<<2048, 256, 0, stream>>>(edges, off, last, second, nl, cur, dc);
    passB_kernel<<<1024, 256, 0, stream>>>((float4*)cur, (const float4*)last,
                                           (const float4*)second, dc, nl, ns,
                                           alpha, i - 1, (i > 1) ? 1 : 0, (float4*)rst);
    float* tmp = second; second = last; last = cur; cur = tmp;
  }
  gemm2_kernel<<<(N_NODES + 63) / 64, 256, 0, stream>>>(rst, last,
                                                        dots + (size_t)(KHOPS + 1) * 192 + 128,
                                                        alpha, W2, b2, out);
}

// Round 3
// 2822.076 us; speedup vs baseline: 1.1632x; 1.0353x over previous
//
#include <hip/hip_runtime.h>
#include <stdint.h>

#define N_NODES 100000
#define N_EDGES 3200000
#define IN_FEATS 500
#define HID 64
#define CLS 40
#define KHOPS 10
#define KT 32
#define NRANGE 8

// ---------------- generic zero ----------------
__global__ void zero_kernel(float4* __restrict__ p, size_t n4) {
  size_t i = (size_t)blockIdx.x * blockDim.x + threadIdx.x;
  size_t stride = (size_t)gridDim.x * blockDim.x;
  float4 z = make_float4(0.f, 0.f, 0.f, 0.f);
  for (; i < n4; i += stride) p[i] = z;
}

// ---------------- CSR build ----------------
__global__ void hist_kernel(const int* __restrict__ dst, int* __restrict__ off) {
  int i = blockIdx.x * blockDim.x + threadIdx.x;
  int stride = gridDim.x * blockDim.x;
  for (int e = i; e < N_EDGES; e += stride) atomicAdd(&off[dst[e] + 1], 1);
}

__launch_bounds__(1024)
__global__ void scan_kernel(int* __restrict__ off, int* __restrict__ cursor) {
  __shared__ int sums[1024];
  const int M = N_NODES + 1;
  int t = threadIdx.x;
  int chunk = (M + 1023) / 1024;
  int beg = t * chunk;
  int end = beg + chunk; if (end > M) end = M;
  int s = 0;
  for (int i = beg; i < end; ++i) s += off[i];
  sums[t] = s;
  __syncthreads();
  for (int d = 1; d < 1024; d <<= 1) {
    int v = (t >= d) ? sums[t - d] : 0;
    __syncthreads();
    sums[t] += v;
    __syncthreads();
  }
  int run = (t == 0) ? 0 : sums[t - 1];
  for (int i = beg; i < end; ++i) {
    run += off[i];
    off[i] = run;
    if (i < N_NODES) cursor[i] = run;
  }
}

// fill: dst-range partitioned to confine the scatter-write working set.
// range r = blockIdx&7 (XCD-affine heuristic): writes land in a contiguous ~3.2MB
// CSR span that stays L2-resident -> full-line evictions instead of 64B/edge to HBM.
__global__ void fill_kernel(const int* __restrict__ src, const int* __restrict__ dst,
                            const float* __restrict__ w, int* __restrict__ cursor,
                            int2* __restrict__ edges) {
  const int r = blockIdx.x & (NRANGE - 1);
  const int slice = blockIdx.x >> 3;
  const int nslices = gridDim.x >> 3;
  const int lo = r * (N_NODES / NRANGE);
  const int hi = lo + (N_NODES / NRANGE);  // N_NODES % 8 == 0
  const int per = (N_EDGES + nslices - 1) / nslices;
  const int beg = slice * per;
  int end = beg + per; if (end > N_EDGES) end = N_EDGES;
  for (int e = beg + threadIdx.x; e < end; e += blockDim.x) {
    int d = dst[e];
    if (d >= lo && d < hi) {
      int p = atomicAdd(&cursor[d], 1);
      edges[p] = make_int2(src[e], __float_as_int(w[e]));
    }
  }
}

// ---------------- fc1: x_raw = relu(F@W1 + b1) + noise*1e-5 ; nn0 += colsum(x^2) ----------------
__launch_bounds__(256)
__global__ void fc1_kernel(const float* __restrict__ F, const float* __restrict__ W1,
                           const float* __restrict__ bias1, const float* __restrict__ noise,
                           float* __restrict__ x, float* __restrict__ nn0) {
  __shared__ float Fs[KT][132];
  __shared__ float Ws[KT][64];
  __shared__ float red[64];
  const int t = threadIdx.x;
  const int tx = t & 15;
  const int ty = t >> 4;
  const int c0 = tx * 4;
  const int n0 = ty * 8;
  const int nodeBase = blockIdx.x * 128;
  const int fk = (t & 7) * 4;
  const int fn = t >> 3;
  const int wr = t >> 3;
  const int wc = (t & 7) * 8;

  float4 fr[4];
  float4 w0r, w1r;
  {
    const int kb = 0;
#pragma unroll
    for (int p = 0; p < 4; ++p) {
      int n = nodeBase + fn + 32 * p;
      int k = kb + fk;
      float4 v = make_float4(0.f, 0.f, 0.f, 0.f);
      if (n < N_NODES && k + 3 < IN_FEATS) v = *(const float4*)(F + (size_t)n * IN_FEATS + k);
      fr[p] = v;
    }
    int k = kb + wr;
    float4 a = make_float4(0.f, 0.f, 0.f, 0.f), b = a;
    if (k < IN_FEATS) {
      a = *(const float4*)(W1 + (size_t)k * HID + wc);
      b = *(const float4*)(W1 + (size_t)k * HID + wc + 4);
    }
    w0r = a; w1r = b;
  }

  float acc[8][4];
#pragma unroll
  for (int i = 0; i < 8; ++i)
#pragma unroll
    for (int j = 0; j < 4; ++j) acc[i][j] = 0.f;

  const int NTILE = (IN_FEATS + KT - 1) / KT;
  for (int tile = 0; tile < NTILE; ++tile) {
    __syncthreads();
#pragma unroll
    for (int p = 0; p < 4; ++p) {
      Fs[fk + 0][fn + 32 * p] = fr[p].x;
      Fs[fk + 1][fn + 32 * p] = fr[p].y;
      Fs[fk + 2][fn + 32 * p] = fr[p].z;
      Fs[fk + 3][fn + 32 * p] = fr[p].w;
    }
    *(float4*)&Ws[wr][wc] = w0r;
    *(float4*)&Ws[wr][wc + 4] = w1r;
    __syncthreads();
    if (tile + 1 < NTILE) {
      const int kb = (tile + 1) * KT;
#pragma unroll
      for (int p = 0; p < 4; ++p) {
        int n = nodeBase + fn + 32 * p;
        int k = kb + fk;
        float4 v = make_float4(0.f, 0.f, 0.f, 0.f);
        if (n < N_NODES && k + 3 < IN_FEATS) v = *(const float4*)(F + (size_t)n * IN_FEATS + k);
        fr[p] = v;
      }
      int k = kb + wr;
      float4 a = make_float4(0.f, 0.f, 0.f, 0.f), b = a;
      if (k < IN_FEATS) {
        a = *(const float4*)(W1 + (size_t)k * HID + wc);
        b = *(const float4*)(W1 + (size_t)k * HID + wc + 4);
      }
      w0r = a; w1r = b;
    }
#pragma unroll 8
    for (int kk = 0; kk < KT; ++kk) {
      float4 fa = *(float4*)&Fs[kk][n0];
      float4 fb = *(float4*)&Fs[kk][n0 + 4];
      float4 wv = *(float4*)&Ws[kk][c0];
      acc[0][0] = fmaf(fa.x, wv.x, acc[0][0]); acc[0][1] = fmaf(fa.x, wv.y, acc[0][1]);
      acc[0][2] = fmaf(fa.x, wv.z, acc[0][2]); acc[0][3] = fmaf(fa.x, wv.w, acc[0][3]);
      acc[1][0] = fmaf(fa.y, wv.x, acc[1][0]); acc[1][1] = fmaf(fa.y, wv.y, acc[1][1]);
      acc[1][2] = fmaf(fa.y, wv.z, acc[1][2]); acc[1][3] = fmaf(fa.y, wv.w, acc[1][3]);
      acc[2][0] = fmaf(fa.z, wv.x, acc[2][0]); acc[2][1] = fmaf(fa.z, wv.y, acc[2][1]);
      acc[2][2] = fmaf(fa.z, wv.z, acc[2][2]); acc[2][3] = fmaf(fa.z, wv.w, acc[2][3]);
      acc[3][0] = fmaf(fa.w, wv.x, acc[3][0]); acc[3][1] = fmaf(fa.w, wv.y, acc[3][1]);
      acc[3][2] = fmaf(fa.w, wv.z, acc[3][2]); acc[3][3] = fmaf(fa.w, wv.w, acc[3][3]);
      acc[4][0] = fmaf(fb.x, wv.x, acc[4][0]); acc[4][1] = fmaf(fb.x, wv.y, acc[4][1]);
      acc[4][2] = fmaf(fb.x, wv.z, acc[4][2]); acc[4][3] = fmaf(fb.x, wv.w, acc[4][3]);
      acc[5][0] = fmaf(fb.y, wv.x, acc[5][0]); acc[5][1] = fmaf(fb.y, wv.y, acc[5][1]);
      acc[5][2] = fmaf(fb.y, wv.z, acc[5][2]); acc[5][3] = fmaf(fb.y, wv.w, acc[5][3]);
      acc[6][0] = fmaf(fb.z, wv.x, acc[6][0]); acc[6][1] = fmaf(fb.z, wv.y, acc[6][1]);
      acc[6][2] = fmaf(fb.z, wv.z, acc[6][2]); acc[6][3] = fmaf(fb.z, wv.w, acc[6][3]);
      acc[7][0] = fmaf(fb.w, wv.x, acc[7][0]); acc[7][1] = fmaf(fb.w, wv.y, acc[7][1]);
      acc[7][2] = fmaf(fb.w, wv.z, acc[7][2]); acc[7][3] = fmaf(fb.w, wv.w, acc[7][3]);
    }
  }

  float4 bb = *(const float4*)(bias1 + c0);
  float np0 = 0.f, np1 = 0.f, np2 = 0.f, np3 = 0.f;
#pragma unroll
  for (int i = 0; i < 8; ++i) {
    int n = nodeBase + n0 + i;
    if (n < N_NODES) {
      float4 nz = *(const float4*)(noise + (size_t)n * HID + c0);
      float v0 = fmaxf(acc[i][0] + bb.x, 0.f) + nz.x * 1e-5f;
      float v1 = fmaxf(acc[i][1] + bb.y, 0.f) + nz.y * 1e-5f;
      float v2 = fmaxf(acc[i][2] + bb.z, 0.f) + nz.z * 1e-5f;
      float v3 = fmaxf(acc[i][3] + bb.w, 0.f) + nz.w * 1e-5f;
      *(float4*)(x + (size_t)n * HID + c0) = make_float4(v0, v1, v2, v3);
      np0 = fmaf(v0, v0, np0); np1 = fmaf(v1, v1, np1);
      np2 = fmaf(v2, v2, np2); np3 = fmaf(v3, v3, np3);
    }
  }
  if (t < 64) red[t] = 0.f;
  __syncthreads();
  atomicAdd(&red[c0 + 0], np0); atomicAdd(&red[c0 + 1], np1);
  atomicAdd(&red[c0 + 2], np2); atomicAdd(&red[c0 + 3], np3);
  __syncthreads();
  if (t < 64) atomicAdd(&nn0[t], red[t]);
}

// ---------------- SpMM: scalar-uniform edge loads, no shuffles ----------------
// wid forced to SGPR via readfirstlane -> n, off[n], edges[j] are compiler-provable
// wave-uniform -> s_load for edge data, gather = SGPR-base + lane*4 coalesced.
__launch_bounds__(256)
__global__ void spmm_kernel(const int2* __restrict__ edges, const int* __restrict__ off,
                            const float* __restrict__ lastr, const float* __restrict__ secondr,
                            const float* __restrict__ nn_l,
                            float* __restrict__ h, float* __restrict__ dslot) {
  __shared__ float red[128];
  const int t = threadIdx.x;
  const int lane = t & 63;
  const int wid = __builtin_amdgcn_readfirstlane(t >> 6);
  if (t < 128) red[t] = 0.f;
  __syncthreads();
  const float sig = 1.f / fmaxf(sqrtf(nn_l[lane]), 1e-8f);
  float d1 = 0.f, d2 = 0.f;
  const int nw = gridDim.x * 4;
  for (int n = blockIdx.x * 4 + wid; n < N_NODES; n += nw) {
    const int beg = off[n], end = off[n + 1];
    float a0 = 0.f, a1 = 0.f, a2 = 0.f, a3 = 0.f;
    float a4 = 0.f, a5 = 0.f, a6 = 0.f, a7 = 0.f;
    int j = beg;
    for (; j + 8 <= end; j += 8) {
      int2 e0 = edges[j + 0]; int2 e1 = edges[j + 1];
      int2 e2 = edges[j + 2]; int2 e3 = edges[j + 3];
      int2 e4 = edges[j + 4]; int2 e5 = edges[j + 5];
      int2 e6 = edges[j + 6]; int2 e7 = edges[j + 7];
      a0 = fmaf(__int_as_float(e0.y), lastr[(size_t)e0.x * HID + lane], a0);
      a1 = fmaf(__int_as_float(e1.y), lastr[(size_t)e1.x * HID + lane], a1);
      a2 = fmaf(__int_as_float(e2.y), lastr[(size_t)e2.x * HID + lane], a2);
      a3 = fmaf(__int_as_float(e3.y), lastr[(size_t)e3.x * HID + lane], a3);
      a4 = fmaf(__int_as_float(e4.y), lastr[(size_t)e4.x * HID + lane], a4);
      a5 = fmaf(__int_as_float(e5.y), lastr[(size_t)e5.x * HID + lane], a5);
      a6 = fmaf(__int_as_float(e6.y), lastr[(size_t)e6.x * HID + lane], a6);
      a7 = fmaf(__int_as_float(e7.y), lastr[(size_t)e7.x * HID + lane], a7);
    }
    for (; j < end; ++j) {
      int2 e = edges[j];
      a0 = fmaf(__int_as_float(e.y), lastr[(size_t)e.x * HID + lane], a0);
    }
    float acc = ((a0 + a1) + (a2 + a3)) + ((a4 + a5) + (a6 + a7));
    acc *= sig;
    size_t o = (size_t)n * HID + lane;
    float l = lastr[o], s = secondr[o];
    h[o] = acc;
    d1 = fmaf(acc, l, d1);
    d2 = fmaf(acc, s, d2);
  }
  atomicAdd(&red[lane], d1);
  atomicAdd(&red[64 + lane], d2);
  __syncthreads();
  if (t < 128) atomicAdd(&dslot[t], red[t]);
}

// ---------------- passB ----------------
__launch_bounds__(256)
__global__ void passB_kernel(float4* __restrict__ h4, const float4* __restrict__ l4,
                             const float4* __restrict__ s4, float* __restrict__ dcur,
                             const float* __restrict__ nn_l, const float* __restrict__ nn_s,
                             const float* __restrict__ alpha, int prevcol, int accum,
                             float4* __restrict__ rst4) {
  __shared__ float red[64];
  int t = threadIdx.x;
  int q = t & 15;
  int c0 = q * 4;
  float4 NL = ((const float4*)nn_l)[q];
  float4 NS = ((const float4*)nn_s)[q];
  float4 D1 = ((const float4*)dcur)[q];
  float4 D2 = ((const float4*)(dcur + 64))[q];
  float4 sigl, sigs;
  sigl.x = 1.f / fmaxf(sqrtf(NL.x), 1e-8f); sigl.y = 1.f / fmaxf(sqrtf(NL.y), 1e-8f);
  sigl.z = 1.f / fmaxf(sqrtf(NL.z), 1e-8f); sigl.w = 1.f / fmaxf(sqrtf(NL.w), 1e-8f);
  sigs.x = 1.f / fmaxf(sqrtf(NS.x), 1e-8f); sigs.y = 1.f / fmaxf(sqrtf(NS.y), 1e-8f);
  sigs.z = 1.f / fmaxf(sqrtf(NS.z), 1e-8f); sigs.w = 1.f / fmaxf(sqrtf(NS.w), 1e-8f);
  float4 C1, C2, AL;
  C1.x = sigl.x * sigl.x * D1.x; C1.y = sigl.y * sigl.y * D1.y;
  C1.z = sigl.z * sigl.z * D1.z; C1.w = sigl.w * sigl.w * D1.w;
  C2.x = sigs.x * sigs.x * D2.x; C2.y = sigs.y * sigs.y * D2.y;
  C2.z = sigs.z * sigs.z * D2.z; C2.w = sigs.w * sigs.w * D2.w;
  AL.x = alpha[(size_t)(c0 + 0) * (KHOPS + 1) + prevcol] * sigl.x;
  AL.y = alpha[(size_t)(c0 + 1) * (KHOPS + 1) + prevcol] * sigl.y;
  AL.z = alpha[(size_t)(c0 + 2) * (KHOPS + 1) + prevcol] * sigl.z;
  AL.w = alpha[(size_t)(c0 + 3) * (KHOPS + 1) + prevcol] * sigl.w;
  float nx = 0.f, ny = 0.f, nz = 0.f, nw = 0.f;
  int row0 = blockIdx.x * 16 + (t >> 4);
  int rstride = gridDim.x * 16;
  for (int n = row0; n < N_NODES; n += rstride) {
    size_t idx = (size_t)n * 16 + q;
    float4 h = h4[idx];
    float4 l = l4[idx];
    float4 s = s4[idx];
    h.x -= C1.x * l.x + C2.x * s.x;
    h.y -= C1.y * l.y + C2.y * s.y;
    h.z -= C1.z * l.z + C2.z * s.z;
    h.w -= C1.w * l.w + C2.w * s.w;
    h4[idx] = h;
    nx = fmaf(h.x, h.x, nx); ny = fmaf(h.y, h.y, ny);
    nz = fmaf(h.z, h.z, nz); nw = fmaf(h.w, h.w, nw);
    float4 r;
    if (accum) {
      r = rst4[idx];
      r.x = fmaf(AL.x, l.x, r.x); r.y = fmaf(AL.y, l.y, r.y);
      r.z = fmaf(AL.z, l.z, r.z); r.w = fmaf(AL.w, l.w, r.w);
    } else {
      r.x = AL.x * l.x; r.y = AL.y * l.y; r.z = AL.z * l.z; r.w = AL.w * l.w;
    }
    rst4[idx] = r;
  }
  if (t < 64) red[t] = 0.f;
  __syncthreads();
  atomicAdd(&red[c0 + 0], nx); atomicAdd(&red[c0 + 1], ny);
  atomicAdd(&red[c0 + 2], nz); atomicAdd(&red[c0 + 3], nw);
  __syncthreads();
  if (t < 64) atomicAdd(&dcur[128 + t], red[t]);
}

// ---------------- fc2 ----------------
__launch_bounds__(256)
__global__ void gemm2_kernel(const float* __restrict__ rst, const float* __restrict__ hK,
                             const float* __restrict__ nnK, const float* __restrict__ alpha,
                             const float* __restrict__ W2, const float* __restrict__ bias2,
                             float* __restrict__ out) {
  __shared__ float W2s[HID * CLS];
  __shared__ float R[64][65];
  __shared__ float coef[64];
  int t = threadIdx.x;
  if (t < 64) coef[t] = alpha[(size_t)t * (KHOPS + 1) + KHOPS] / fmaxf(sqrtf(nnK[t]), 1e-8f);
  for (int i = t; i < HID * CLS; i += 256) W2s[i] = W2[i];
  int nodeBase = blockIdx.x * 64;
  __syncthreads();
  for (int i = t; i < 64 * 16; i += 256) {
    int r = i >> 4, c4 = (i & 15) * 4;
    int n = nodeBase + r;
    if (n < N_NODES) {
      float4 rv = *(const float4*)(rst + (size_t)n * HID + c4);
      float4 hv = *(const float4*)(hK + (size_t)n * HID + c4);
      R[r][c4 + 0] = rv.x + coef[c4 + 0] * hv.x;
      R[r][c4 + 1] = rv.y + coef[c4 + 1] * hv.y;
      R[r][c4 + 2] = rv.z + coef[c4 + 2] * hv.z;
      R[r][c4 + 3] = rv.w + coef[c4 + 3] * hv.w;
    } else {
      R[r][c4 + 0] = 0.f; R[r][c4 + 1] = 0.f; R[r][c4 + 2] = 0.f; R[r][c4 + 3] = 0.f;
    }
  }
  __syncthreads();
  int node = t >> 2;
  int cls0 = (t & 3) * 10;
  float o[10];
#pragma unroll
  for (int j = 0; j < 10; ++j) o[j] = bias2[cls0 + j];
#pragma unroll 4
  for (int k = 0; k < HID; ++k) {
    float rv = R[node][k];
    const float* wrow = &W2s[k * CLS + cls0];
#pragma unroll
    for (int j = 0; j < 10; ++j) o[j] = fmaf(rv, wrow[j], o[j]);
  }
  int n = nodeBase + node;
  if (n < N_NODES) {
#pragma unroll
    for (int j = 0; j < 10; ++j) out[(size_t)n * CLS + cls0 + j] = o[j];
  }
}

extern "C" void kernel_launch(void* const* d_in, const int* in_sizes, int n_in,
                              void* d_out, int out_size, void* d_ws, size_t ws_size,
                              hipStream_t stream) {
  (void)in_sizes; (void)n_in; (void)out_size;
  const float* features  = (const float*)d_in[0];
  const float* noise     = (const float*)d_in[1];
  const float* norm_A    = (const float*)d_in[2];
  const float* W1        = (const float*)d_in[3];
  const float* b1        = (const float*)d_in[4];
  const float* W2        = (const float*)d_in[5];
  const float* b2        = (const float*)d_in[6];
  const float* alpha     = (const float*)d_in[7];
  const int*   edge_index= (const int*)d_in[8];
  float* out = (float*)d_out;

  char* ws = (char*)d_ws;
  const size_t NB = (size_t)N_NODES * HID * sizeof(float);
  const size_t CURSOR_PAD = 400128;
  float* hA    = (float*)(ws);
  float* hC    = (float*)(ws + NB);
  float* rst   = (float*)(ws + 2 * NB);
  int2*  edges = (int2*)(ws + 3 * NB);
  int*   cursor= (int*)(ws + 4 * NB);
  char*  zbase = ws + 4 * NB + CURSOR_PAD;
  float* hB    = (float*)(zbase);
  int*   off   = (int*)(zbase + NB);
  float* dots  = (float*)(zbase + NB + 400128);
  const size_t zspan = NB + 400128 + (size_t)12 * 192 * 4;
  const size_t total = 4 * NB + CURSOR_PAD + zspan;
  if (ws_size < total) return;

  zero_kernel<<<4096, 256, 0, stream>>>((float4*)zbase, zspan / 16);
  hist_kernel<<<2048, 256, 0, stream>>>(edge_index + N_EDGES, off);
  scan_kernel<<<1, 1024, 0, stream>>>(off, cursor);
  fill_kernel<<<2048, 256, 0, stream>>>(edge_index, edge_index + N_EDGES, norm_A, cursor, edges);
  fc1_kernel<<<(N_NODES + 127) / 128, 256, 0, stream>>>(features, W1, b1, noise, hA,
                                                        dots + 1 * 192 + 128);
  float* second = hB; float* last = hA; float* cur = hC;
  for (int i = 1; i <= KHOPS; ++i) {
    float* dc = dots + (size_t)(i + 1) * 192;
    float* nl = dots + (size_t)(i)     * 192 + 128;
    float* ns = dots + (size_t)(i - 1) * 192 + 128;
    spmm_kernel<<<2048, 256, 0, stream>>>(edges, off, last, second, nl, cur, dc);
    passB_kernel<<<1024, 256, 0, stream>>>((float4*)cur, (const float4*)last,
                                           (const float4*)second, dc, nl, ns,
                                           alpha, i - 1, (i > 1) ? 1 : 0, (float4*)rst);
    float* tmp = second; second = last; last = cur; cur = tmp;
  }
  gemm2_kernel<<<(N_NODES + 63) / 64, 256, 0, stream>>>(rst, last,
                                                        dots + (size_t)(KHOPS + 1) * 192 + 128,
                                                        alpha, W2, b2, out);
}

// Round 4
// 2636.324 us; speedup vs baseline: 1.2452x; 1.0705x over previous
//
#include <hip/hip_runtime.h>
#include <stdint.h>

#define N_NODES 100000
#define N_EDGES 3200000
#define IN_FEATS 500
#define HID 64
#define CLS 40
#define KHOPS 10
#define KT 32
#define NRANGE 8
#define SCAN_BS 256
#define SCAN_NBLK 391   // 391*256 = 100096 >= N_NODES+1

// ---------------- generic zero ----------------
__global__ void zero_kernel(float4* __restrict__ p, size_t n4) {
  size_t i = (size_t)blockIdx.x * blockDim.x + threadIdx.x;
  size_t stride = (size_t)gridDim.x * blockDim.x;
  float4 z = make_float4(0.f, 0.f, 0.f, 0.f);
  for (; i < n4; i += stride) p[i] = z;
}

// ---------------- CSR build ----------------
// hist: dst-range partitioned (blockIdx&7 = range) -> atomics confined to a
// ~50KB slice of off[] that stays resident in one XCD's L2 (no line ping-pong).
__global__ void hist_kernel(const int* __restrict__ dst, int* __restrict__ off) {
  const int r = blockIdx.x & (NRANGE - 1);
  const int slice = blockIdx.x >> 3;
  const int nslices = gridDim.x >> 3;
  const int lo = r * (N_NODES / NRANGE);
  const int hi = lo + (N_NODES / NRANGE);
  const int per = (N_EDGES + nslices - 1) / nslices;
  const int beg = slice * per;
  int end = beg + per; if (end > N_EDGES) end = N_EDGES;
  for (int e = beg + threadIdx.x; e < end; e += blockDim.x) {
    int d = dst[e];
    if (d >= lo && d < hi) atomicAdd(&off[d + 1], 1);
  }
}

// 3-phase parallel scan over off[0..N], inclusive, in place; cursor[i]=off[i] for i<N.
__launch_bounds__(SCAN_BS)
__global__ void scanA_kernel(const int* __restrict__ off, int* __restrict__ psum) {
  __shared__ int s[SCAN_BS];
  int b = blockIdx.x, t = threadIdx.x;
  int idx = b * SCAN_BS + t;
  s[t] = (idx < N_NODES + 1) ? off[idx] : 0;
  __syncthreads();
  for (int d = SCAN_BS / 2; d > 0; d >>= 1) {
    if (t < d) s[t] += s[t + d];
    __syncthreads();
  }
  if (t == 0) psum[b] = s[0];
}

__launch_bounds__(512)
__global__ void scanB_kernel(int* __restrict__ psum) {
  __shared__ int s[512];
  int t = threadIdx.x;
  s[t] = (t < SCAN_NBLK) ? psum[t] : 0;
  __syncthreads();
  for (int d = 1; d < 512; d <<= 1) {
    int v = (t >= d) ? s[t - d] : 0;
    __syncthreads();
    s[t] += v;
    __syncthreads();
  }
  if (t < SCAN_NBLK) psum[t] = (t == 0) ? 0 : s[t - 1];  // exclusive block offsets
}

__launch_bounds__(SCAN_BS)
__global__ void scanC_kernel(int* __restrict__ off, int* __restrict__ cursor,
                             const int* __restrict__ psum) {
  __shared__ int s[SCAN_BS];
  int b = blockIdx.x, t = threadIdx.x;
  int idx = b * SCAN_BS + t;
  s[t] = (idx < N_NODES + 1) ? off[idx] : 0;
  __syncthreads();
  for (int d = 1; d < SCAN_BS; d <<= 1) {
    int v = (t >= d) ? s[t - d] : 0;
    __syncthreads();
    s[t] += v;
    __syncthreads();
  }
  int run = s[t] + psum[b];
  if (idx < N_NODES + 1) {
    off[idx] = run;
    if (idx < N_NODES) cursor[idx] = run;
  }
}

// fill: dst-range partitioned (see round-2 note) — confined scatter writes.
__global__ void fill_kernel(const int* __restrict__ src, const int* __restrict__ dst,
                            const float* __restrict__ w, int* __restrict__ cursor,
                            int2* __restrict__ edges) {
  const int r = blockIdx.x & (NRANGE - 1);
  const int slice = blockIdx.x >> 3;
  const int nslices = gridDim.x >> 3;
  const int lo = r * (N_NODES / NRANGE);
  const int hi = lo + (N_NODES / NRANGE);
  const int per = (N_EDGES + nslices - 1) / nslices;
  const int beg = slice * per;
  int end = beg + per; if (end > N_EDGES) end = N_EDGES;
  for (int e = beg + threadIdx.x; e < end; e += blockDim.x) {
    int d = dst[e];
    if (d >= lo && d < hi) {
      int p = atomicAdd(&cursor[d], 1);
      edges[p] = make_int2(src[e], __float_as_int(w[e]));
    }
  }
}

// ---------------- fc1 ----------------
__launch_bounds__(256)
__global__ void fc1_kernel(const float* __restrict__ F, const float* __restrict__ W1,
                           const float* __restrict__ bias1, const float* __restrict__ noise,
                           float* __restrict__ x, float* __restrict__ nn0) {
  __shared__ float Fs[KT][132];
  __shared__ float Ws[KT][64];
  __shared__ float red[64];
  const int t = threadIdx.x;
  const int tx = t & 15;
  const int ty = t >> 4;
  const int c0 = tx * 4;
  const int n0 = ty * 8;
  const int nodeBase = blockIdx.x * 128;
  const int fk = (t & 7) * 4;
  const int fn = t >> 3;
  const int wr = t >> 3;
  const int wc = (t & 7) * 8;

  float4 fr[4];
  float4 w0r, w1r;
  {
#pragma unroll
    for (int p = 0; p < 4; ++p) {
      int n = nodeBase + fn + 32 * p;
      float4 v = make_float4(0.f, 0.f, 0.f, 0.f);
      if (n < N_NODES && fk + 3 < IN_FEATS) v = *(const float4*)(F + (size_t)n * IN_FEATS + fk);
      fr[p] = v;
    }
    float4 a = make_float4(0.f, 0.f, 0.f, 0.f), b = a;
    if (wr < IN_FEATS) {
      a = *(const float4*)(W1 + (size_t)wr * HID + wc);
      b = *(const float4*)(W1 + (size_t)wr * HID + wc + 4);
    }
    w0r = a; w1r = b;
  }

  float acc[8][4];
#pragma unroll
  for (int i = 0; i < 8; ++i)
#pragma unroll
    for (int j = 0; j < 4; ++j) acc[i][j] = 0.f;

  const int NTILE = (IN_FEATS + KT - 1) / KT;
  for (int tile = 0; tile < NTILE; ++tile) {
    __syncthreads();
#pragma unroll
    for (int p = 0; p < 4; ++p) {
      Fs[fk + 0][fn + 32 * p] = fr[p].x;
      Fs[fk + 1][fn + 32 * p] = fr[p].y;
      Fs[fk + 2][fn + 32 * p] = fr[p].z;
      Fs[fk + 3][fn + 32 * p] = fr[p].w;
    }
    *(float4*)&Ws[wr][wc] = w0r;
    *(float4*)&Ws[wr][wc + 4] = w1r;
    __syncthreads();
    if (tile + 1 < NTILE) {
      const int kb = (tile + 1) * KT;
#pragma unroll
      for (int p = 0; p < 4; ++p) {
        int n = nodeBase + fn + 32 * p;
        int k = kb + fk;
        float4 v = make_float4(0.f, 0.f, 0.f, 0.f);
        if (n < N_NODES && k + 3 < IN_FEATS) v = *(const float4*)(F + (size_t)n * IN_FEATS + k);
        fr[p] = v;
      }
      int k = kb + wr;
      float4 a = make_float4(0.f, 0.f, 0.f, 0.f), b = a;
      if (k < IN_FEATS) {
        a = *(const float4*)(W1 + (size_t)k * HID + wc);
        b = *(const float4*)(W1 + (size_t)k * HID + wc + 4);
      }
      w0r = a; w1r = b;
    }
#pragma unroll 8
    for (int kk = 0; kk < KT; ++kk) {
      float4 fa = *(float4*)&Fs[kk][n0];
      float4 fb = *(float4*)&Fs[kk][n0 + 4];
      float4 wv = *(float4*)&Ws[kk][c0];
      acc[0][0] = fmaf(fa.x, wv.x, acc[0][0]); acc[0][1] = fmaf(fa.x, wv.y, acc[0][1]);
      acc[0][2] = fmaf(fa.x, wv.z, acc[0][2]); acc[0][3] = fmaf(fa.x, wv.w, acc[0][3]);
      acc[1][0] = fmaf(fa.y, wv.x, acc[1][0]); acc[1][1] = fmaf(fa.y, wv.y, acc[1][1]);
      acc[1][2] = fmaf(fa.y, wv.z, acc[1][2]); acc[1][3] = fmaf(fa.y, wv.w, acc[1][3]);
      acc[2][0] = fmaf(fa.z, wv.x, acc[2][0]); acc[2][1] = fmaf(fa.z, wv.y, acc[2][1]);
      acc[2][2] = fmaf(fa.z, wv.z, acc[2][2]); acc[2][3] = fmaf(fa.z, wv.w, acc[2][3]);
      acc[3][0] = fmaf(fa.w, wv.x, acc[3][0]); acc[3][1] = fmaf(fa.w, wv.y, acc[3][1]);
      acc[3][2] = fmaf(fa.w, wv.z, acc[3][2]); acc[3][3] = fmaf(fa.w, wv.w, acc[3][3]);
      acc[4][0] = fmaf(fb.x, wv.x, acc[4][0]); acc[4][1] = fmaf(fb.x, wv.y, acc[4][1]);
      acc[4][2] = fmaf(fb.x, wv.z, acc[4][2]); acc[4][3] = fmaf(fb.x, wv.w, acc[4][3]);
      acc[5][0] = fmaf(fb.y, wv.x, acc[5][0]); acc[5][1] = fmaf(fb.y, wv.y, acc[5][1]);
      acc[5][2] = fmaf(fb.y, wv.z, acc[5][2]); acc[5][3] = fmaf(fb.y, wv.w, acc[5][3]);
      acc[6][0] = fmaf(fb.z, wv.x, acc[6][0]); acc[6][1] = fmaf(fb.z, wv.y, acc[6][1]);
      acc[6][2] = fmaf(fb.z, wv.z, acc[6][2]); acc[6][3] = fmaf(fb.z, wv.w, acc[6][3]);
      acc[7][0] = fmaf(fb.w, wv.x, acc[7][0]); acc[7][1] = fmaf(fb.w, wv.y, acc[7][1]);
      acc[7][2] = fmaf(fb.w, wv.z, acc[7][2]); acc[7][3] = fmaf(fb.w, wv.w, acc[7][3]);
    }
  }

  float4 bb = *(const float4*)(bias1 + c0);
  float np0 = 0.f, np1 = 0.f, np2 = 0.f, np3 = 0.f;
#pragma unroll
  for (int i = 0; i < 8; ++i) {
    int n = nodeBase + n0 + i;
    if (n < N_NODES) {
      float4 nz = *(const float4*)(noise + (size_t)n * HID + c0);
      float v0 = fmaxf(acc[i][0] + bb.x, 0.f) + nz.x * 1e-5f;
      float v1 = fmaxf(acc[i][1] + bb.y, 0.f) + nz.y * 1e-5f;
      float v2 = fmaxf(acc[i][2] + bb.z, 0.f) + nz.z * 1e-5f;
      float v3 = fmaxf(acc[i][3] + bb.w, 0.f) + nz.w * 1e-5f;
      *(float4*)(x + (size_t)n * HID + c0) = make_float4(v0, v1, v2, v3);
      np0 = fmaf(v0, v0, np0); np1 = fmaf(v1, v1, np1);
      np2 = fmaf(v2, v2, np2); np3 = fmaf(v3, v3, np3);
    }
  }
  if (t < 64) red[t] = 0.f;
  __syncthreads();
  atomicAdd(&red[c0 + 0], np0); atomicAdd(&red[c0 + 1], np1);
  atomicAdd(&red[c0 + 2], np2); atomicAdd(&red[c0 + 3], np3);
  __syncthreads();
  if (t < 64) atomicAdd(&nn0[t], red[t]);
}

// ---------------- SpMM ----------------
__launch_bounds__(256)
__global__ void spmm_kernel(const int2* __restrict__ edges, const int* __restrict__ off,
                            const float* __restrict__ lastr, const float* __restrict__ secondr,
                            const float* __restrict__ nn_l,
                            float* __restrict__ h, float* __restrict__ dslot) {
  __shared__ float red[128];
  const int t = threadIdx.x;
  const int lane = t & 63;
  const int wid = __builtin_amdgcn_readfirstlane(t >> 6);
  if (t < 128) red[t] = 0.f;
  __syncthreads();
  const float sig = 1.f / fmaxf(sqrtf(nn_l[lane]), 1e-8f);
  float d1 = 0.f, d2 = 0.f;
  const int nw = gridDim.x * 4;
  for (int n = blockIdx.x * 4 + wid; n < N_NODES; n += nw) {
    const int beg = off[n], end = off[n + 1];
    float a0 = 0.f, a1 = 0.f, a2 = 0.f, a3 = 0.f;
    float a4 = 0.f, a5 = 0.f, a6 = 0.f, a7 = 0.f;
    int j = beg;
    for (; j + 8 <= end; j += 8) {
      int2 e0 = edges[j + 0]; int2 e1 = edges[j + 1];
      int2 e2 = edges[j + 2]; int2 e3 = edges[j + 3];
      int2 e4 = edges[j + 4]; int2 e5 = edges[j + 5];
      int2 e6 = edges[j + 6]; int2 e7 = edges[j + 7];
      a0 = fmaf(__int_as_float(e0.y), lastr[(size_t)e0.x * HID + lane], a0);
      a1 = fmaf(__int_as_float(e1.y), lastr[(size_t)e1.x * HID + lane], a1);
      a2 = fmaf(__int_as_float(e2.y), lastr[(size_t)e2.x * HID + lane], a2);
      a3 = fmaf(__int_as_float(e3.y), lastr[(size_t)e3.x * HID + lane], a3);
      a4 = fmaf(__int_as_float(e4.y), lastr[(size_t)e4.x * HID + lane], a4);
      a5 = fmaf(__int_as_float(e5.y), lastr[(size_t)e5.x * HID + lane], a5);
      a6 = fmaf(__int_as_float(e6.y), lastr[(size_t)e6.x * HID + lane], a6);
      a7 = fmaf(__int_as_float(e7.y), lastr[(size_t)e7.x * HID + lane], a7);
    }
    for (; j < end; ++j) {
      int2 e = edges[j];
      a0 = fmaf(__int_as_float(e.y), lastr[(size_t)e.x * HID + lane], a0);
    }
    float acc = ((a0 + a1) + (a2 + a3)) + ((a4 + a5) + (a6 + a7));
    acc *= sig;
    size_t o = (size_t)n * HID + lane;
    float l = lastr[o], s = secondr[o];
    h[o] = acc;
    d1 = fmaf(acc, l, d1);
    d2 = fmaf(acc, s, d2);
  }
  atomicAdd(&red[lane], d1);
  atomicAdd(&red[64 + lane], d2);
  __syncthreads();
  if (t < 128) atomicAdd(&dslot[t], red[t]);
}

// ---------------- passB ----------------
__launch_bounds__(256)
__global__ void passB_kernel(float4* __restrict__ h4, const float4* __restrict__ l4,
                             const float4* __restrict__ s4, float* __restrict__ dcur,
                             const float* __restrict__ nn_l, const float* __restrict__ nn_s,
                             const float* __restrict__ alpha, int prevcol, int accum,
                             float4* __restrict__ rst4) {
  __shared__ float red[64];
  int t = threadIdx.x;
  int q = t & 15;
  int c0 = q * 4;
  float4 NL = ((const float4*)nn_l)[q];
  float4 NS = ((const float4*)nn_s)[q];
  float4 D1 = ((const float4*)dcur)[q];
  float4 D2 = ((const float4*)(dcur + 64))[q];
  float4 sigl, sigs;
  sigl.x = 1.f / fmaxf(sqrtf(NL.x), 1e-8f); sigl.y = 1.f / fmaxf(sqrtf(NL.y), 1e-8f);
  sigl.z = 1.f / fmaxf(sqrtf(NL.z), 1e-8f); sigl.w = 1.f / fmaxf(sqrtf(NL.w), 1e-8f);
  sigs.x = 1.f / fmaxf(sqrtf(NS.x), 1e-8f); sigs.y = 1.f / fmaxf(sqrtf(NS.y), 1e-8f);
  sigs.z = 1.f / fmaxf(sqrtf(NS.z), 1e-8f); sigs.w = 1.f / fmaxf(sqrtf(NS.w), 1e-8f);
  float4 C1, C2, AL;
  C1.x = sigl.x * sigl.x * D1.x; C1.y = sigl.y * sigl.y * D1.y;
  C1.z = sigl.z * sigl.z * D1.z; C1.w = sigl.w * sigl.w * D1.w;
  C2.x = sigs.x * sigs.x * D2.x; C2.y = sigs.y * sigs.y * D2.y;
  C2.z = sigs.z * sigs.z * D2.z; C2.w = sigs.w * sigs.w * D2.w;
  AL.x = alpha[(size_t)(c0 + 0) * (KHOPS + 1) + prevcol] * sigl.x;
  AL.y = alpha[(size_t)(c0 + 1) * (KHOPS + 1) + prevcol] * sigl.y;
  AL.z = alpha[(size_t)(c0 + 2) * (KHOPS + 1) + prevcol] * sigl.z;
  AL.w = alpha[(size_t)(c0 + 3) * (KHOPS + 1) + prevcol] * sigl.w;
  float nx = 0.f, ny = 0.f, nz = 0.f, nw = 0.f;
  int row0 = blockIdx.x * 16 + (t >> 4);
  int rstride = gridDim.x * 16;
  for (int n = row0; n < N_NODES; n += rstride) {
    size_t idx = (size_t)n * 16 + q;
    float4 h = h4[idx];
    float4 l = l4[idx];
    float4 s = s4[idx];
    h.x -= C1.x * l.x + C2.x * s.x;
    h.y -= C1.y * l.y + C2.y * s.y;
    h.z -= C1.z * l.z + C2.z * s.z;
    h.w -= C1.w * l.w + C2.w * s.w;
    h4[idx] = h;
    nx = fmaf(h.x, h.x, nx); ny = fmaf(h.y, h.y, ny);
    nz = fmaf(h.z, h.z, nz); nw = fmaf(h.w, h.w, nw);
    float4 r;
    if (accum) {
      r = rst4[idx];
      r.x = fmaf(AL.x, l.x, r.x); r.y = fmaf(AL.y, l.y, r.y);
      r.z = fmaf(AL.z, l.z, r.z); r.w = fmaf(AL.w, l.w, r.w);
    } else {
      r.x = AL.x * l.x; r.y = AL.y * l.y; r.z = AL.z * l.z; r.w = AL.w * l.w;
    }
    rst4[idx] = r;
  }
  if (t < 64) red[t] = 0.f;
  __syncthreads();
  atomicAdd(&red[c0 + 0], nx); atomicAdd(&red[c0 + 1], ny);
  atomicAdd(&red[c0 + 2], nz); atomicAdd(&red[c0 + 3], nw);
  __syncthreads();
  if (t < 64) atomicAdd(&dcur[128 + t], red[t]);
}

// ---------------- fc2 ----------------
__launch_bounds__(256)
__global__ void gemm2_kernel(const float* __restrict__ rst, const float* __restrict__ hK,
                             const float* __restrict__ nnK, const float* __restrict__ alpha,
                             const float* __restrict__ W2, const float* __restrict__ bias2,
                             float* __restrict__ out) {
  __shared__ float W2s[HID * CLS];
  __shared__ float R[64][65];
  __shared__ float coef[64];
  int t = threadIdx.x;
  if (t < 64) coef[t] = alpha[(size_t)t * (KHOPS + 1) + KHOPS] / fmaxf(sqrtf(nnK[t]), 1e-8f);
  for (int i = t; i < HID * CLS; i += 256) W2s[i] = W2[i];
  int nodeBase = blockIdx.x * 64;
  __syncthreads();
  for (int i = t; i < 64 * 16; i += 256) {
    int r = i >> 4, c4 = (i & 15) * 4;
    int n = nodeBase + r;
    if (n < N_NODES) {
      float4 rv = *(const float4*)(rst + (size_t)n * HID + c4);
      float4 hv = *(const float4*)(hK + (size_t)n * HID + c4);
      R[r][c4 + 0] = rv.x + coef[c4 + 0] * hv.x;
      R[r][c4 + 1] = rv.y + coef[c4 + 1] * hv.y;
      R[r][c4 + 2] = rv.z + coef[c4 + 2] * hv.z;
      R[r][c4 + 3] = rv.w + coef[c4 + 3] * hv.w;
    } else {
      R[r][c4 + 0] = 0.f; R[r][c4 + 1] = 0.f; R[r][c4 + 2] = 0.f; R[r][c4 + 3] = 0.f;
    }
  }
  __syncthreads();
  int node = t >> 2;
  int cls0 = (t & 3) * 10;
  float o[10];
#pragma unroll
  for (int j = 0; j < 10; ++j) o[j] = bias2[cls0 + j];
#pragma unroll 4
  for (int k = 0; k < HID; ++k) {
    float rv = R[node][k];
    const float* wrow = &W2s[k * CLS + cls0];
#pragma unroll
    for (int j = 0; j < 10; ++j) o[j] = fmaf(rv, wrow[j], o[j]);
  }
  int n = nodeBase + node;
  if (n < N_NODES) {
#pragma unroll
    for (int j = 0; j < 10; ++j) out[(size_t)n * CLS + cls0 + j] = o[j];
  }
}

extern "C" void kernel_launch(void* const* d_in, const int* in_sizes, int n_in,
                              void* d_out, int out_size, void* d_ws, size_t ws_size,
                              hipStream_t stream) {
  (void)in_sizes; (void)n_in; (void)out_size;
  const float* features  = (const float*)d_in[0];
  const float* noise     = (const float*)d_in[1];
  const float* norm_A    = (const float*)d_in[2];
  const float* W1        = (const float*)d_in[3];
  const float* b1        = (const float*)d_in[4];
  const float* W2        = (const float*)d_in[5];
  const float* b2        = (const float*)d_in[6];
  const float* alpha     = (const float*)d_in[7];
  const int*   edge_index= (const int*)d_in[8];
  float* out = (float*)d_out;

  char* ws = (char*)d_ws;
  const size_t NB = (size_t)N_NODES * HID * sizeof(float);
  const size_t CURSOR_PAD = 400128;
  float* hA    = (float*)(ws);
  float* hC    = (float*)(ws + NB);
  float* rst   = (float*)(ws + 2 * NB);
  int2*  edges = (int2*)(ws + 3 * NB);
  int*   cursor= (int*)(ws + 4 * NB);
  char*  zbase = ws + 4 * NB + CURSOR_PAD;
  float* hB    = (float*)(zbase);
  int*   off   = (int*)(zbase + NB);
  float* dots  = (float*)(zbase + NB + 400128);
  const size_t zspan = NB + 400128 + (size_t)12 * 192 * 4;
  int*   psum  = (int*)(zbase + zspan);                      // SCAN_NBLK ints (no pre-zero needed)
  const size_t total = 4 * NB + CURSOR_PAD + zspan + 4096;
  if (ws_size < total) return;

  zero_kernel<<<4096, 256, 0, stream>>>((float4*)zbase, zspan / 16);
  hist_kernel<<<2048, 256, 0, stream>>>(edge_index + N_EDGES, off);
  scanA_kernel<<<SCAN_NBLK, SCAN_BS, 0, stream>>>(off, psum);
  scanB_kernel<<<1, 512, 0, stream>>>(psum);
  scanC_kernel<<<SCAN_NBLK, SCAN_BS, 0, stream>>>(off, cursor, psum);
  fill_kernel<<<2048, 256, 0, stream>>>(edge_index, edge_index + N_EDGES, norm_A, cursor, edges);
  fc1_kernel<<<(N_NODES + 127) / 128, 256, 0, stream>>>(features, W1, b1, noise, hA,
                                                        dots + 1 * 192 + 128);
  float* second = hB; float* last = hA; float* cur = hC;
  for (int i = 1; i <= KHOPS; ++i) {
    float* dc = dots + (size_t)(i + 1) * 192;
    float* nl = dots + (size_t)(i)     * 192 + 128;
    float* ns = dots + (size_t)(i - 1) * 192 + 128;
    spmm_kernel<<<2048, 256, 0, stream>>>(edges, off, last, second, nl, cur, dc);
    passB_kernel<<<1024, 256, 0, stream>>>((float4*)cur, (const float4*)last,
                                           (const float4*)second, dc, nl, ns,
                                           alpha, i - 1, (i > 1) ? 1 : 0, (float4*)rst);
    float* tmp = second; second = last; last = cur; cur = tmp;
  }
  gemm2_kernel<<<(N_NODES + 63) / 64, 256, 0, stream>>>(rst, last,
                                                        dots + (size_t)(KHOPS + 1) * 192 + 128,
                                                        alpha, W2, b2, out);
}